// Round 8
// baseline (287.974 us; speedup 1.0000x reference)
//
#include <hip/hip_runtime.h>
#include <math.h>

#define Bn 4
#define Tn 4096
#define En 256
#define An 64
#define SS 8      // kv stripes per q-tile
#define PLS 72    // P/O LDS row stride in shorts (144 B, 16B-aligned)
#define WLS 264   // W LDS row stride in shorts (528 B, 16B-aligned)

typedef __attribute__((ext_vector_type(8))) short short8;
typedef __attribute__((ext_vector_type(8))) __bf16 bf16x8;
typedef __attribute__((ext_vector_type(4))) float f32x4;
typedef __attribute__((ext_vector_type(4))) short short4v;
typedef __attribute__((ext_vector_type(2))) unsigned int uint2v;

__device__ __forceinline__ f32x4 mfma16(short8 a, short8 b, f32x4 c) {
    return __builtin_amdgcn_mfma_f32_16x16x32_bf16(
        __builtin_bit_cast(bf16x8, a), __builtin_bit_cast(bf16x8, b), c, 0, 0, 0);
}
__device__ __forceinline__ unsigned short f2bf(float x) {   // RNE fp32->bf16
    unsigned int u = __builtin_bit_cast(unsigned int, x);
    u += 0x7fffu + ((u >> 16) & 1u);
    return (unsigned short)(u >> 16);
}
__device__ __forceinline__ float bf2f(unsigned short h) {
    return __builtin_bit_cast(float, (unsigned int)h << 16);
}
__device__ __forceinline__ unsigned int packbf2(float lo, float hi) {
    return (unsigned int)f2bf(lo) | ((unsigned int)f2bf(hi) << 16);
}

// ---------------------------------------------------------------------------
// Kernel 1: QKV projection with in-kernel W staging (prep folded in).
// grid 512, 256 thr.  b=(bid&7)>>1 (XCD-local), jh=bid&1 (column half:
// jh0 -> Wq[0:64]+Wk[0:32]; jh1 -> Wk[32:64]+Wv[0:64]), ib=bid>>3 (row block).
// Also zeroes the fan-in counters consumed by the flash kernel.
// Outputs: q bf16 [b][t][a] pre-scaled 0.125*log2e, k bf16 [b][t][a],
//          v_t bf16 [b][a][t].
// ---------------------------------------------------------------------------
__global__ __launch_bounds__(256, 2) void proj_kernel(
    const float* __restrict__ emb,
    const float* __restrict__ Wq, const float* __restrict__ Wk, const float* __restrict__ Wv,
    const float* __restrict__ bq, const float* __restrict__ bk, const float* __restrict__ bv,
    unsigned short* __restrict__ qg, unsigned short* __restrict__ kg,
    unsigned short* __restrict__ v_t, int* __restrict__ cnt)
{
    const int bid  = blockIdx.x;
    const int tid  = threadIdx.x;
    const int wave = tid >> 6, lane = tid & 63, quad = lane >> 4, l15 = lane & 15;
    const int b    = (bid & 7) >> 1;
    const int jh   = bid & 1;
    const int ib   = bid >> 3;
    const int row0  = b * Tn + ib * 64;
    const int trow0 = ib * 64;

    if (tid == 0) cnt[bid] = 0;     // fan-in counters for flash (stream-ordered)

    __shared__ unsigned short Wl[96 * WLS];   // W^T staging [lr][e], 50688 B
    __shared__ unsigned short vtr[64 * PLS];  // V tile transpose, 9216 B

    // ---- stage the 96 needed W columns, transposed+bf16: Wl[lr][e] ----
    {   // segment A: 64 cols (jh0: Wq 0..63 -> lr 0..63; jh1: Wv 0..63 -> lr 32..95)
        const float* __restrict__ srcA = jh ? Wv : Wq;
        const int lrbA = jh ? 32 : 0;
#pragma unroll
        for (int it = 0; it < 16; it++) {
            const int idx = it * 256 + tid;
            const int e   = idx >> 4;
            const int c4  = (idx & 15) * 4;
            float4 w = *(const float4*)&srcA[(size_t)e * An + c4];
            Wl[(lrbA + c4 + 0) * WLS + e] = f2bf(w.x);
            Wl[(lrbA + c4 + 1) * WLS + e] = f2bf(w.y);
            Wl[(lrbA + c4 + 2) * WLS + e] = f2bf(w.z);
            Wl[(lrbA + c4 + 3) * WLS + e] = f2bf(w.w);
        }
        // segment B: 32 cols of Wk (jh0: cols 0..31 -> lr 64..95; jh1: 32..63 -> lr 0..31)
        const int coloff = jh ? 32 : 0;
        const int lrbB   = jh ? 0 : 64;
#pragma unroll
        for (int it = 0; it < 8; it++) {
            const int idx = it * 256 + tid;
            const int e   = idx >> 3;
            const int c4  = (idx & 7) * 4;
            float4 w = *(const float4*)&Wk[(size_t)e * An + coloff + c4];
            Wl[(lrbB + c4 + 0) * WLS + e] = f2bf(w.x);
            Wl[(lrbB + c4 + 1) * WLS + e] = f2bf(w.y);
            Wl[(lrbB + c4 + 2) * WLS + e] = f2bf(w.z);
            Wl[(lrbB + c4 + 3) * WLS + e] = f2bf(w.w);
        }
    }

    // ---- A-fragments: emb rows fp32 -> bf16, A[m=l15][k=quad*8+j] ----
    short8 A[8];
    {
        const float* erow = emb + (size_t)(row0 + wave * 16 + l15) * En;
#pragma unroll
        for (int c = 0; c < 8; c++) {
            const float* pp = erow + c * 32 + quad * 8;
            float4 f0 = *(const float4*)pp;
            float4 f1 = *(const float4*)(pp + 4);
            A[c] = (short8){(short)f2bf(f0.x), (short)f2bf(f0.y), (short)f2bf(f0.z), (short)f2bf(f0.w),
                            (short)f2bf(f1.x), (short)f2bf(f1.y), (short)f2bf(f1.z), (short)f2bf(f1.w)};
        }
    }
    __syncthreads();

    f32x4 acc[6];
#pragma unroll
    for (int x = 0; x < 6; x++) acc[x] = (f32x4){0.f, 0.f, 0.f, 0.f};

#pragma unroll
    for (int x = 0; x < 6; x++) {
        const unsigned short* wrow = &Wl[(x * 16 + l15) * WLS];   // lr = x*16+l15 both halves
#pragma unroll
        for (int c = 0; c < 8; c++)
            acc[x] = mfma16(A[c], *(const short8*)(wrow + c * 32 + quad * 8), acc[x]);
    }

    const float QS = 0.125f * 1.4426950408889634f;   // 1/sqrt(A) * log2(e)
#pragma unroll
    for (int x = 0; x < 6; x++) {
        const int nt = jh * 6 + x;
        const int m  = nt >> 2;
        const int al = (nt & 3) * 16 + l15;
        const float bsv = ((m == 0) ? bq : (m == 1) ? bk : bv)[al];
#pragma unroll
        for (int rg = 0; rg < 4; rg++) {
            const int row_l = wave * 16 + quad * 4 + rg;   // C/D: row=quad*4+reg, col=l15
            const float val = acc[x][rg] + bsv;
            if (m == 0)      qg[(size_t)(row0 + row_l) * An + al] = f2bf(val * QS);
            else if (m == 1) kg[(size_t)(row0 + row_l) * An + al] = f2bf(val);
            else             vtr[al * PLS + row_l] = f2bf(val);
        }
    }
    if (jh == 1) {
        __syncthreads();
        const int a  = tid >> 2;
        const int tg = (tid & 3) * 16;
        unsigned short* dst = v_t + (size_t)(b * 64 + a) * Tn + trow0 + tg;
        *(short8*)dst       = *(const short8*)&vtr[a * PLS + tg];
        *(short8*)(dst + 8) = *(const short8*)&vtr[a * PLS + tg + 8];
    }
}

// ---------------------------------------------------------------------------
// Kernel 2: flash attention + atomic fan-in stripe merge.  grid 512, 256 thr.
// Waves independent, equal length (pair p / 127-p), kv-striped by SS.
// After a wave stores its stripe partial it release-fences + atomicAdd's the
// tile counter; the SS-th arriver acquire-fences and merges -> out fp32.
// XCD locality: batch = (bid&7)>>1.
// ---------------------------------------------------------------------------
__global__ __launch_bounds__(256, 2) void flash_kernel(
    const unsigned short* __restrict__ qg, const unsigned short* __restrict__ kg,
    const unsigned short* __restrict__ v_t,
    unsigned short* __restrict__ Opart, float* __restrict__ ml,
    int* __restrict__ cnt, float* __restrict__ out)
{
    const int bid  = blockIdx.x;
    const int tid  = threadIdx.x;
    const int wave = tid >> 6, lane = tid & 63, quad = lane >> 4, l15 = lane & 15;
    const int b    = (bid & 7) >> 1;
    const int jh   = bid & 1;
    const int ib   = bid >> 3;

    __shared__ unsigned short lds[4 * 32 * PLS];
    unsigned short* tw = lds + wave * (32 * PLS);

    const unsigned short* kb0 = kg  + ((size_t)b << 12) * An;
    const unsigned short* vb0 = v_t + (size_t)b * An * Tn;

    const int u = (ib * 2 + jh) * 4 + wave;   // 0..511
    const int p = u >> 3;                     // 0..63
    const int s = u & 7;                      // stripe

    int koff[4][2], voff[4][2];
#pragma unroll
    for (int nt = 0; nt < 4; nt++)
#pragma unroll
        for (int c = 0; c < 2; c++) {
            koff[nt][c] = (nt * 16 + l15) * An + c * 32 + quad * 8;
            voff[nt][c] = (nt * 16 + l15) * Tn + c * 32 + quad * 8;
        }

#pragma unroll 1
    for (int tile = 0; tile < 2; tile++) {
        const int qt32  = tile ? (127 - p) : p;
        const int qrow0 = qt32 * 32;
        const int tmax  = qt32 >> 1;

        short8 qB[2][2];
        {
            const unsigned short* qb = qg + (((size_t)b << 12) + qrow0) * An;
#pragma unroll
            for (int g = 0; g < 2; g++)
#pragma unroll
                for (int c = 0; c < 2; c++)
                    qB[g][c] = *(const short8*)(qb + (size_t)(16 * g + l15) * An + c * 32 + quad * 8);
        }

        float m_s[2] = {-__builtin_inff(), -__builtin_inff()};
        float l_s[2] = {0.f, 0.f};
        f32x4 O[4][2];
#pragma unroll
        for (int nt = 0; nt < 4; nt++)
#pragma unroll
            for (int g = 0; g < 2; g++) O[nt][g] = (f32x4){0.f, 0.f, 0.f, 0.f};

        int t = s;
        if (t <= tmax) {
            short8 KA[4][2];
            {
                const unsigned short* kb = kb0 + (size_t)t * (64 * An);
#pragma unroll
                for (int nt = 0; nt < 4; nt++)
#pragma unroll
                    for (int c = 0; c < 2; c++) KA[nt][c] = *(const short8*)(kb + koff[nt][c]);
            }
            for (;;) {
                // V fragments for t (consumed late -> latency hidden)
                short8 VA[4][2];
                {
                    const unsigned short* vb = vb0 + (size_t)t * 64;
#pragma unroll
                    for (int nt = 0; nt < 4; nt++)
#pragma unroll
                        for (int c = 0; c < 2; c++) VA[nt][c] = *(const short8*)(vb + voff[nt][c]);
                }

                // S^T = K Q^T : 16 MFMA.  S^T[kv=16nt+quad*4+rg][qrow=16g+l15]
                f32x4 St[4][2];
#pragma unroll
                for (int nt = 0; nt < 4; nt++)
#pragma unroll
                    for (int g = 0; g < 2; g++) {
                        f32x4 a0 = (f32x4){0.f, 0.f, 0.f, 0.f};
                        a0 = mfma16(KA[nt][0], qB[g][0], a0);
                        a0 = mfma16(KA[nt][1], qB[g][1], a0);
                        St[nt][g] = a0;
                    }

                // prefetch next K tile
                const int tn = t + SS;
                const bool more = (tn <= tmax);
                short8 KN[4][2];
                if (more) {
                    const unsigned short* kb = kb0 + (size_t)tn * (64 * An);
#pragma unroll
                    for (int nt = 0; nt < 4; nt++)
#pragma unroll
                        for (int c = 0; c < 2; c++) KN[nt][c] = *(const short8*)(kb + koff[nt][c]);
                }

                // causal mask on the diagonal tile
                if (t == tmax) {
                    const int kvb = t * 64 + quad * 4;
#pragma unroll
                    for (int nt = 0; nt < 4; nt++)
#pragma unroll
                        for (int g = 0; g < 2; g++) {
                            const int qr = qrow0 + 16 * g + l15;
#pragma unroll
                            for (int rg = 0; rg < 4; rg++)
                                if (kvb + nt * 16 + rg > qr) St[nt][g][rg] = -__builtin_inff();
                        }
                }

                // online softmax (exp2 domain); P -> per-wave LDS [qrow][kv]
#pragma unroll
                for (int g = 0; g < 2; g++) {
                    float mt = -__builtin_inff();
#pragma unroll
                    for (int nt = 0; nt < 4; nt++)
                        mt = fmaxf(mt, fmaxf(fmaxf(St[nt][g][0], St[nt][g][1]),
                                             fmaxf(St[nt][g][2], St[nt][g][3])));
                    mt = fmaxf(mt, __shfl_xor(mt, 16));
                    mt = fmaxf(mt, __shfl_xor(mt, 32));
                    const float mn = fmaxf(m_s[g], mt);
                    const float alpha = exp2f(m_s[g] - mn);
                    m_s[g] = mn;
                    float rs = 0.f;
#pragma unroll
                    for (int nt = 0; nt < 4; nt++) {
#pragma unroll
                        for (int rg = 0; rg < 4; rg++) {
                            const float pv = exp2f(St[nt][g][rg] - mn);
                            St[nt][g][rg] = pv;
                            rs += pv;
                        }
                        const unsigned int d0 = packbf2(St[nt][g][0], St[nt][g][1]);
                        const unsigned int d1 = packbf2(St[nt][g][2], St[nt][g][3]);
                        *(short4v*)&tw[(16 * g + l15) * PLS + 16 * nt + quad * 4] =
                            __builtin_bit_cast(short4v, (uint2v){d0, d1});
                    }
                    rs += __shfl_xor(rs, 16);
                    rs += __shfl_xor(rs, 32);
                    l_s[g] = l_s[g] * alpha + rs;
                    if (!__all(alpha == 1.f)) {
#pragma unroll
                        for (int nt = 0; nt < 4; nt++)
#pragma unroll
                            for (int rg = 0; rg < 4; rg++) O[nt][g][rg] *= alpha;
                    }
                }

                // P^T B-fragments from LDS (same-wave RAW, no barrier); PV
#pragma unroll
                for (int g = 0; g < 2; g++)
#pragma unroll
                    for (int c = 0; c < 2; c++) {
                        const short8 pb = *(const short8*)&tw[(16 * g + l15) * PLS + c * 32 + quad * 8];
#pragma unroll
                        for (int nt = 0; nt < 4; nt++)
                            O[nt][g] = mfma16(VA[nt][c], pb, O[nt][g]);
                    }

                if (!more) break;
                t = tn;
#pragma unroll
                for (int nt = 0; nt < 4; nt++)
#pragma unroll
                    for (int c = 0; c < 2; c++) KA[nt][c] = KN[nt][c];
            }
        }

        // ---- epilogue: O^T -> [qrow][a] via per-wave LDS, store partial ----
#pragma unroll
        for (int nt = 0; nt < 4; nt++)
#pragma unroll
            for (int g = 0; g < 2; g++) {
                const unsigned int d0 = packbf2(O[nt][g][0], O[nt][g][1]);
                const unsigned int d1 = packbf2(O[nt][g][2], O[nt][g][3]);
                *(short4v*)&tw[(16 * g + l15) * PLS + 16 * nt + quad * 4] =
                    __builtin_bit_cast(short4v, (uint2v){d0, d1});
            }
        const size_t unit = (size_t)(b * 128 + qt32) * SS + s;
        {
            unsigned short* ob = Opart + unit * 2048;
            const int row = lane >> 1;
#pragma unroll
            for (int pp = 0; pp < 4; pp++) {
                const int colh = (lane & 1) * 8 + pp * 16;
                *(short8*)(ob + row * 64 + colh) = *(const short8*)&tw[row * PLS + colh];
            }
            if (quad == 0) {
                float* mlb = ml + unit * 64;
#pragma unroll
                for (int g = 0; g < 2; g++) {
                    mlb[16 * g + l15]      = m_s[g];
                    mlb[32 + 16 * g + l15] = l_s[g];
                }
            }
        }

        // ---- fan-in: last stripe to arrive merges this (b, qt32) tile ----
        __threadfence();                       // release partial stores
        int old = 0;
        if (lane == 0) old = atomicAdd(&cnt[b * 128 + qt32], 1);
        old = __shfl(old, 0);
        if (old == SS - 1) {
            __threadfence();                   // acquire others' partials
            const int qr = lane >> 1;          // 0..31
            const int ah = (lane & 1) * 32;    // col half
            const size_t ub = (size_t)(b * 128 + qt32) * SS;

            float mstar = -__builtin_inff();
#pragma unroll
            for (int s2 = 0; s2 < SS; s2++)
                mstar = fmaxf(mstar, ml[(ub + s2) * 64 + qr]);

            float accm[32];
#pragma unroll
            for (int x = 0; x < 32; x++) accm[x] = 0.f;
            float lsum = 0.f;

#pragma unroll 1
            for (int s2 = 0; s2 < SS; s2++) {
                const float ms = ml[(ub + s2) * 64 + qr];
                const float ls = ml[(ub + s2) * 64 + 32 + qr];
                const float w  = exp2f(ms - mstar);
                lsum += ls * w;
                const unsigned short* op = &Opart[(ub + s2) * 2048 + qr * 64 + ah];
#pragma unroll
                for (int h = 0; h < 4; h++) {
                    const short8 ov = *(const short8*)(op + h * 8);
#pragma unroll
                    for (int x = 0; x < 8; x++)
                        accm[h * 8 + x] += w * bf2f((unsigned short)ov[x]);
                }
            }
            const float inv = 1.f / lsum;
            float* o = out + (((size_t)b << 12) + qt32 * 32 + qr) * An + ah;
#pragma unroll
            for (int h = 0; h < 8; h++) {
                float4 r = {accm[h * 4] * inv, accm[h * 4 + 1] * inv,
                            accm[h * 4 + 2] * inv, accm[h * 4 + 3] * inv};
                *(float4*)(o + h * 4) = r;
            }
        }
    }
}

// ---------------------------------------------------------------------------
extern "C" void kernel_launch(void* const* d_in, const int* in_sizes, int n_in,
                              void* d_out, int out_size, void* d_ws, size_t ws_size,
                              hipStream_t stream) {
    const float* emb = (const float*)d_in[0];
    const float* Wk  = (const float*)d_in[1];
    const float* bk  = (const float*)d_in[2];
    const float* Wq  = (const float*)d_in[3];
    const float* bq  = (const float*)d_in[4];
    const float* Wv  = (const float*)d_in[5];
    const float* bv  = (const float*)d_in[6];
    float* out = (float*)d_out;

    char* ws = (char*)d_ws;
    const size_t MB = 1024 * 1024;
    unsigned short* q     = (unsigned short*)(ws);                       // 2 MB
    unsigned short* k     = (unsigned short*)(ws + 2 * MB);              // 2 MB
    unsigned short* v_t   = (unsigned short*)(ws + 4 * MB);              // 2 MB
    int*            cnt   = (int*)(ws + 6 * MB);                         // 2 KB (reserve 64K)
    float*          ml    = (float*)(ws + 6 * MB + 64 * 1024);           // 1 MB
    unsigned short* Opart = (unsigned short*)(ws + 7 * MB + 64 * 1024);  // 16 MB

    proj_kernel<<<512, 256, 0, stream>>>(emb, Wq, Wk, Wv, bq, bk, bv, q, k, v_t, cnt);
    flash_kernel<<<512, 256, 0, stream>>>(q, k, v_t, Opart, ml, cnt, out);
}

// Round 9
// 141.926 us; speedup vs baseline: 2.0291x; 2.0291x over previous
//
#include <hip/hip_runtime.h>
#include <math.h>

#define Bn 4
#define Tn 4096
#define En 256
#define An 64
#define PLS 72    // P/O LDS row stride in shorts (144 B, 16B-aligned)
#define WLS 264   // W LDS row stride in shorts (528 B, 16B-aligned)

typedef __attribute__((ext_vector_type(8))) short short8;
typedef __attribute__((ext_vector_type(8))) __bf16 bf16x8;
typedef __attribute__((ext_vector_type(4))) float f32x4;
typedef __attribute__((ext_vector_type(4))) short short4v;
typedef __attribute__((ext_vector_type(2))) unsigned int uint2v;

__device__ __forceinline__ f32x4 mfma16(short8 a, short8 b, f32x4 c) {
    return __builtin_amdgcn_mfma_f32_16x16x32_bf16(
        __builtin_bit_cast(bf16x8, a), __builtin_bit_cast(bf16x8, b), c, 0, 0, 0);
}
__device__ __forceinline__ unsigned short f2bf(float x) {   // RNE fp32->bf16
    unsigned int u = __builtin_bit_cast(unsigned int, x);
    u += 0x7fffu + ((u >> 16) & 1u);
    return (unsigned short)(u >> 16);
}
__device__ __forceinline__ float bf2f(unsigned short h) {
    return __builtin_bit_cast(float, (unsigned int)h << 16);
}
__device__ __forceinline__ unsigned int packbf2(float lo, float hi) {
    return (unsigned int)f2bf(lo) | ((unsigned int)f2bf(hi) << 16);
}

// ---------------------------------------------------------------------------
// Kernel 1: QKV projection with in-kernel W staging (no prep dispatch).
// grid 512: jh=bid&1 (column half), row-block = bid>>1.
// Outputs: q bf16 [b][t][a] pre-scaled 0.125*log2e, k bf16 [b][t][a],
//          v_t bf16 [b][a][t].
// ---------------------------------------------------------------------------
__global__ __launch_bounds__(256, 2) void proj_kernel(
    const float* __restrict__ emb,
    const float* __restrict__ Wq, const float* __restrict__ Wk, const float* __restrict__ Wv,
    const float* __restrict__ bq, const float* __restrict__ bk, const float* __restrict__ bv,
    unsigned short* __restrict__ qg, unsigned short* __restrict__ kg,
    unsigned short* __restrict__ v_t)
{
    const int bid  = blockIdx.x;
    const int tid  = threadIdx.x;
    const int wave = tid >> 6, lane = tid & 63, quad = lane >> 4, l15 = lane & 15;
    const int jh   = bid & 1;
    const int rb   = bid >> 1;
    const int row0  = rb * 64;            // flat row in [0, B*T)
    const int b     = row0 >> 12;
    const int trow0 = row0 & 4095;

    __shared__ unsigned short Wl[96 * WLS];   // W^T staging [lr][e]
    __shared__ unsigned short vtr[64 * PLS];  // V tile transpose

    // ---- stage the 96 needed W columns, transposed+bf16: Wl[lr][e] ----
    {   // segment A: jh0: Wq cols 0..63 -> lr 0..63; jh1: Wv 0..63 -> lr 32..95
        const float* __restrict__ srcA = jh ? Wv : Wq;
        const int lrbA = jh ? 32 : 0;
#pragma unroll
        for (int it = 0; it < 16; it++) {
            const int idx = it * 256 + tid;
            const int e   = idx >> 4;
            const int c4  = (idx & 15) * 4;
            float4 w = *(const float4*)&srcA[(size_t)e * An + c4];
            Wl[(lrbA + c4 + 0) * WLS + e] = f2bf(w.x);
            Wl[(lrbA + c4 + 1) * WLS + e] = f2bf(w.y);
            Wl[(lrbA + c4 + 2) * WLS + e] = f2bf(w.z);
            Wl[(lrbA + c4 + 3) * WLS + e] = f2bf(w.w);
        }
        // segment B: Wk (jh0: cols 0..31 -> lr 64..95; jh1: cols 32..63 -> lr 0..31)
        const int coloff = jh ? 32 : 0;
        const int lrbB   = jh ? 0 : 64;
#pragma unroll
        for (int it = 0; it < 8; it++) {
            const int idx = it * 256 + tid;
            const int e   = idx >> 3;
            const int c4  = (idx & 7) * 4;
            float4 w = *(const float4*)&Wk[(size_t)e * An + coloff + c4];
            Wl[(lrbB + c4 + 0) * WLS + e] = f2bf(w.x);
            Wl[(lrbB + c4 + 1) * WLS + e] = f2bf(w.y);
            Wl[(lrbB + c4 + 2) * WLS + e] = f2bf(w.z);
            Wl[(lrbB + c4 + 3) * WLS + e] = f2bf(w.w);
        }
    }

    // ---- A-fragments: emb rows fp32 -> bf16, A[m=l15][k=quad*8+j] ----
    short8 A[8];
    {
        const float* erow = emb + (size_t)(row0 + wave * 16 + l15) * En;
#pragma unroll
        for (int c = 0; c < 8; c++) {
            const float* pp = erow + c * 32 + quad * 8;
            float4 f0 = *(const float4*)pp;
            float4 f1 = *(const float4*)(pp + 4);
            A[c] = (short8){(short)f2bf(f0.x), (short)f2bf(f0.y), (short)f2bf(f0.z), (short)f2bf(f0.w),
                            (short)f2bf(f1.x), (short)f2bf(f1.y), (short)f2bf(f1.z), (short)f2bf(f1.w)};
        }
    }
    __syncthreads();

    f32x4 acc[6];
#pragma unroll
    for (int x = 0; x < 6; x++) acc[x] = (f32x4){0.f, 0.f, 0.f, 0.f};

#pragma unroll
    for (int x = 0; x < 6; x++) {
        const unsigned short* wrow = &Wl[(x * 16 + l15) * WLS];
#pragma unroll
        for (int c = 0; c < 8; c++)
            acc[x] = mfma16(A[c], *(const short8*)(wrow + c * 32 + quad * 8), acc[x]);
    }

    const float QS = 0.125f * 1.4426950408889634f;   // 1/sqrt(A) * log2(e)
#pragma unroll
    for (int x = 0; x < 6; x++) {
        const int nt = jh * 6 + x;
        const int m  = nt >> 2;
        const int al = (nt & 3) * 16 + l15;
        const float bsv = ((m == 0) ? bq : (m == 1) ? bk : bv)[al];
#pragma unroll
        for (int rg = 0; rg < 4; rg++) {
            const int row_l = wave * 16 + quad * 4 + rg;   // C/D: row=quad*4+reg, col=l15
            const float val = acc[x][rg] + bsv;
            if (m == 0)      qg[(size_t)(row0 + row_l) * An + al] = f2bf(val * QS);
            else if (m == 1) kg[(size_t)(row0 + row_l) * An + al] = f2bf(val);
            else             vtr[al * PLS + row_l] = f2bf(val);
        }
    }
    if (jh == 1) {
        __syncthreads();
        const int a  = tid >> 2;
        const int tg = (tid & 3) * 16;
        unsigned short* dst = v_t + (size_t)(b * 64 + a) * Tn + trow0 + tg;
        *(short8*)dst       = *(const short8*)&vtr[a * PLS + tg];
        *(short8*)(dst + 8) = *(const short8*)&vtr[a * PLS + tg + 8];
    }
}

// ---------------------------------------------------------------------------
// Kernel 2: flash attention, 64 q-rows per wave (halves VMEM instrs per FLOP
// vs 32-row waves — attacks the TA-throughput plateau).  No barriers; waves
// independent + equal length via complementary pair (p, 63-p); kv-striped by
// S.  Softmax per 16-col group sequentially; P transposed via per-wave LDS.
// grid (8*S, 4).  u = blockIdx.x*4+wave: p = u>>lgS in [0,32), s = u&(S-1).
// Partials: Opart[(b*64+qt)*S+s] = bf16 [64 qrow][64 a]; ml m,l per row.
// ---------------------------------------------------------------------------
__global__ __launch_bounds__(256, 2) void flash_kernel(
    const unsigned short* __restrict__ qg, const unsigned short* __restrict__ kg,
    const unsigned short* __restrict__ v_t,
    unsigned short* __restrict__ Opart, float* __restrict__ ml,
    int S, int lgS)
{
    const int b    = blockIdx.y;
    const int tid  = threadIdx.x;
    const int wave = tid >> 6, lane = tid & 63, quad = lane >> 4, l15 = lane & 15;
    const int u    = blockIdx.x * 4 + wave;
    const int p    = u >> lgS;            // 0..31
    const int s    = u & (S - 1);

    __shared__ unsigned short lds[4 * 64 * PLS];   // per-wave 64-row P/O slice
    unsigned short* tw = lds + wave * (64 * PLS);

    const unsigned short* kb0 = kg  + ((size_t)b << 12) * An;
    const unsigned short* vb0 = v_t + (size_t)b * An * Tn;

#pragma unroll 1
    for (int tile = 0; tile < 2; tile++) {
        const int qt    = tile ? (63 - p) : p;   // 64-row tile index
        const int qrow0 = qt * 64;
        const int tmax  = qt;

        // Q B-fragments: B[k=a][n=qrow], group g = qrows 16g..16g+15
        short8 qB[4][2];
        {
            const unsigned short* qb = qg + (((size_t)b << 12) + qrow0) * An;
#pragma unroll
            for (int g = 0; g < 4; g++)
#pragma unroll
                for (int c = 0; c < 2; c++)
                    qB[g][c] = *(const short8*)(qb + (size_t)(16 * g + l15) * An + c * 32 + quad * 8);
        }

        float m_s[4] = {-__builtin_inff(), -__builtin_inff(), -__builtin_inff(), -__builtin_inff()};
        float l_s[4] = {0.f, 0.f, 0.f, 0.f};
        f32x4 O[4][4];
#pragma unroll
        for (int nt = 0; nt < 4; nt++)
#pragma unroll
            for (int g = 0; g < 4; g++) O[nt][g] = (f32x4){0.f, 0.f, 0.f, 0.f};

        int t = s;
        if (t <= tmax) {
            short8 KA[4][2];
            {
                const unsigned short* kb = kb0 + (size_t)t * (64 * An);
#pragma unroll
                for (int nt = 0; nt < 4; nt++)
#pragma unroll
                    for (int c = 0; c < 2; c++)
                        KA[nt][c] = *(const short8*)(kb + (nt * 16 + l15) * An + c * 32 + quad * 8);
            }
            for (;;) {
                // V^T fragments for t (consumed at end -> latency hidden)
                short8 VA[4][2];
                {
                    const unsigned short* vb = vb0 + (size_t)t * 64;
#pragma unroll
                    for (int nt = 0; nt < 4; nt++)
#pragma unroll
                        for (int c = 0; c < 2; c++)
                            VA[nt][c] = *(const short8*)(vb + (size_t)(nt * 16 + l15) * Tn + c * 32 + quad * 8);
                }

                // prefetch next K tile
                const int tn = t + S;
                const bool more = (tn <= tmax);
                short8 KN[4][2];
                if (more) {
                    const unsigned short* kb = kb0 + (size_t)tn * (64 * An);
#pragma unroll
                    for (int nt = 0; nt < 4; nt++)
#pragma unroll
                        for (int c = 0; c < 2; c++)
                            KN[nt][c] = *(const short8*)(kb + (nt * 16 + l15) * An + c * 32 + quad * 8);
                }

                const bool diag = (t == tmax);

                // per q-column group: S^T slab, softmax, P->LDS, PV
#pragma unroll
                for (int g = 0; g < 4; g++) {
                    // S^T[kv=16nt+quad*4+rg][qrow=16g+l15] : 8 MFMA
                    f32x4 St[4];
#pragma unroll
                    for (int nt = 0; nt < 4; nt++) {
                        f32x4 a0 = (f32x4){0.f, 0.f, 0.f, 0.f};
                        a0 = mfma16(KA[nt][0], qB[g][0], a0);
                        a0 = mfma16(KA[nt][1], qB[g][1], a0);
                        St[nt] = a0;
                    }
                    if (diag) {
                        const int qr = 16 * g + l15;        // local q-row
                        const int kvb = quad * 4;
#pragma unroll
                        for (int nt = 0; nt < 4; nt++)
#pragma unroll
                            for (int rg = 0; rg < 4; rg++)
                                if (nt * 16 + kvb + rg > qr) St[nt][rg] = -__builtin_inff();
                    }
                    // online softmax (exp2 domain)
                    float mt = -__builtin_inff();
#pragma unroll
                    for (int nt = 0; nt < 4; nt++)
                        mt = fmaxf(mt, fmaxf(fmaxf(St[nt][0], St[nt][1]),
                                             fmaxf(St[nt][2], St[nt][3])));
                    mt = fmaxf(mt, __shfl_xor(mt, 16));
                    mt = fmaxf(mt, __shfl_xor(mt, 32));
                    const float mn = fmaxf(m_s[g], mt);
                    const float alpha = exp2f(m_s[g] - mn);
                    m_s[g] = mn;
                    float rs = 0.f;
#pragma unroll
                    for (int nt = 0; nt < 4; nt++) {
#pragma unroll
                        for (int rg = 0; rg < 4; rg++) {
                            const float pv = exp2f(St[nt][rg] - mn);
                            St[nt][rg] = pv;
                            rs += pv;
                        }
                        const unsigned int d0 = packbf2(St[nt][0], St[nt][1]);
                        const unsigned int d1 = packbf2(St[nt][2], St[nt][3]);
                        *(short4v*)&tw[(16 * g + l15) * PLS + 16 * nt + quad * 4] =
                            __builtin_bit_cast(short4v, (uint2v){d0, d1});
                    }
                    rs += __shfl_xor(rs, 16);
                    rs += __shfl_xor(rs, 32);
                    l_s[g] = l_s[g] * alpha + rs;
                    if (!__all(alpha == 1.f)) {
#pragma unroll
                        for (int nt = 0; nt < 4; nt++)
#pragma unroll
                            for (int rg = 0; rg < 4; rg++) O[nt][g][rg] *= alpha;
                    }
                    // P^T B-fragments from LDS (same-wave RAW); O^T += V^T P^T
#pragma unroll
                    for (int c = 0; c < 2; c++) {
                        const short8 pb = *(const short8*)&tw[(16 * g + l15) * PLS + c * 32 + quad * 8];
#pragma unroll
                        for (int nt = 0; nt < 4; nt++)
                            O[nt][g] = mfma16(VA[nt][c], pb, O[nt][g]);
                    }
                }

                if (!more) break;
                t = tn;
#pragma unroll
                for (int nt = 0; nt < 4; nt++)
#pragma unroll
                    for (int c = 0; c < 2; c++) KA[nt][c] = KN[nt][c];
            }
        }

        // ---- epilogue: O^T -> [qrow][a] via per-wave LDS, store partial ----
#pragma unroll
        for (int nt = 0; nt < 4; nt++)
#pragma unroll
            for (int g = 0; g < 4; g++) {
                const unsigned int d0 = packbf2(O[nt][g][0], O[nt][g][1]);
                const unsigned int d1 = packbf2(O[nt][g][2], O[nt][g][3]);
                *(short4v*)&tw[(16 * g + l15) * PLS + 16 * nt + quad * 4] =
                    __builtin_bit_cast(short4v, (uint2v){d0, d1});
            }
        {
            const size_t unit = (size_t)(b * 64 + qt) * (size_t)S + s;
            unsigned short* ob = Opart + unit * 4096;
#pragma unroll
            for (int rr = 0; rr < 2; rr++) {
                const int row = rr * 32 + (lane >> 1);
#pragma unroll
                for (int pp = 0; pp < 4; pp++) {
                    const int colh = (lane & 1) * 8 + pp * 16;
                    *(short8*)(ob + row * 64 + colh) = *(const short8*)&tw[row * PLS + colh];
                }
            }
            if (quad == 0) {
                float* mlb = ml + unit * 128;
#pragma unroll
                for (int g = 0; g < 4; g++) {
                    mlb[16 * g + l15]      = m_s[g];
                    mlb[64 + 16 * g + l15] = l_s[g];
                }
            }
        }
    }
}

// ---------------------------------------------------------------------------
// Kernel 3: merge the S kv-stripe partials -> out fp32 [b][t][a].
// grid (64, 4): per (b, qt).  Thread: qr = tid>>2 (0..63), a16 = (tid&3)*16.
// ---------------------------------------------------------------------------
__global__ __launch_bounds__(256) void merge_kernel(
    const unsigned short* __restrict__ Opart, const float* __restrict__ ml,
    float* __restrict__ out, int S)
{
    const int qt = blockIdx.x, b = blockIdx.y;
    const int tid = threadIdx.x;
    const int qr  = tid >> 2;            // 0..63
    const int a16 = (tid & 3) * 16;
    const size_t ub = (size_t)(b * 64 + qt) * (size_t)S;

    float mstar = -__builtin_inff();
    for (int s = 0; s < S; s++)
        mstar = fmaxf(mstar, ml[(ub + s) * 128 + qr]);

    float acc[16];
#pragma unroll
    for (int x = 0; x < 16; x++) acc[x] = 0.f;
    float lsum = 0.f;

#pragma unroll 1
    for (int s = 0; s < S; s++) {
        const float ms = ml[(ub + s) * 128 + qr];
        const float ls = ml[(ub + s) * 128 + 64 + qr];
        const float w  = exp2f(ms - mstar);
        lsum += ls * w;
        if (w != 0.f) {
            const unsigned short* op = &Opart[(ub + s) * 4096 + qr * 64 + a16];
            const short8 o0 = *(const short8*)op;
            const short8 o1 = *(const short8*)(op + 8);
#pragma unroll
            for (int x = 0; x < 8; x++) {
                acc[x]     += w * bf2f((unsigned short)o0[x]);
                acc[8 + x] += w * bf2f((unsigned short)o1[x]);
            }
        }
    }
    const float inv = 1.f / lsum;
    float* o = out + (((size_t)b << 12) + qt * 64 + qr) * An + a16;
#pragma unroll
    for (int h = 0; h < 4; h++) {
        float4 r = {acc[h * 4] * inv, acc[h * 4 + 1] * inv,
                    acc[h * 4 + 2] * inv, acc[h * 4 + 3] * inv};
        *(float4*)(o + h * 4) = r;
    }
}

// ---------------------------------------------------------------------------
extern "C" void kernel_launch(void* const* d_in, const int* in_sizes, int n_in,
                              void* d_out, int out_size, void* d_ws, size_t ws_size,
                              hipStream_t stream) {
    const float* emb = (const float*)d_in[0];
    const float* Wk  = (const float*)d_in[1];
    const float* bk  = (const float*)d_in[2];
    const float* Wq  = (const float*)d_in[3];
    const float* bq  = (const float*)d_in[4];
    const float* Wv  = (const float*)d_in[5];
    const float* bv  = (const float*)d_in[6];
    float* out = (float*)d_out;

    char* ws = (char*)d_ws;
    const size_t MB = 1024 * 1024;

    // stripe count: prefer 16 (2048 waves = full co-residency at 2 blk/CU)
    int S = 8, lgS = 3;
    {
        const size_t need16 = 6 * MB + 64 * 1024
                            + (size_t)16 * 128 * 1024      // ml: 4*64*16*512 B
                            + (size_t)16 * 2 * MB;          // Opart: 4*64*16*8 KB
        if (need16 <= ws_size) { S = 16; lgS = 4; }
    }

    unsigned short* q     = (unsigned short*)(ws);                        // 2 MB
    unsigned short* k     = (unsigned short*)(ws + 2 * MB);               // 2 MB
    unsigned short* v_t   = (unsigned short*)(ws + 4 * MB);               // 2 MB
    float*          ml    = (float*)(ws + 6 * MB + 64 * 1024);            // S*128 KB
    unsigned short* Opart = (unsigned short*)(ws + 6 * MB + 64 * 1024 + (size_t)S * 128 * 1024);

    proj_kernel<<<512, 256, 0, stream>>>(emb, Wq, Wk, Wv, bq, bk, bv, q, k, v_t);
    flash_kernel<<<dim3(8 * S, 4), 256, 0, stream>>>(q, k, v_t, Opart, ml, S, lgS);
    merge_kernel<<<dim3(64, 4), 256, 0, stream>>>(Opart, ml, out, S);
}